// Round 5
// baseline (270.540 us; speedup 1.0000x reference)
//
#include <hip/hip_runtime.h>
#include <hip/hip_bf16.h>

#define NS 100000
#define CC 64
#define K3 27
#define EPSV 1e-4f

typedef __attribute__((ext_vector_type(4))) float f32x4;
typedef __attribute__((ext_vector_type(8))) short bf16x8;

// round-to-nearest-even f32 -> bf16 bits
__device__ __forceinline__ short f2bf(float f) {
    union { float f; unsigned u; } uf; uf.f = f;
    unsigned r = (uf.u + 0x7fffu + ((uf.u >> 16) & 1u)) >> 16;
    return (short)r;
}

// ---- kernel 1: fold BN params into per-channel scale/bias (2 sets) ----
__global__ void prep_coeffs(const float* __restrict__ g1, const float* __restrict__ b1,
                            const float* __restrict__ m1, const float* __restrict__ v1,
                            const float* __restrict__ g2, const float* __restrict__ b2,
                            const float* __restrict__ m2, const float* __restrict__ v2,
                            float* __restrict__ coeffs) {
    int t = threadIdx.x;           // 128 threads
    int ch = t & 63;
    if (t < 64) {
        float s = g1[ch] * rsqrtf(v1[ch] + EPSV);
        coeffs[ch] = s;
        coeffs[64 + ch] = b1[ch] - m1[ch] * s;
    } else {
        float s = g2[ch] * rsqrtf(v2[ch] + EPSV);
        coeffs[128 + ch] = s;
        coeffs[192 + ch] = b2[ch] - m2[ch] * s;
    }
}

// ---- kernel 2: pack W1/W2 (f32 [27][64][64], layout k,c,d) into bf16 MFMA
// B-fragments. Fragment fi = k*8 + kc*4 + t4; lane l holds 8 contiguous-k
// elements B[kc*32 + 8*(l>>4) + j][t4*16 + (l&15)]. Stored at (fi*64+l)*8. ----
__global__ void pack_w(const float* __restrict__ W1, const float* __restrict__ W2,
                       short* __restrict__ Wp1, short* __restrict__ Wp2) {
    int t = blockIdx.x * blockDim.x + threadIdx.x;
    if (t >= 2 * K3 * 8 * 64) return;
    int lane = t & 63;
    int f = t >> 6;                 // 0..431
    int which = f / (K3 * 8);
    int f2 = f % (K3 * 8);          // k*8 + kc*4 + t4
    int k = f2 >> 3, kc = (f2 >> 2) & 1, t4 = f2 & 3;
    const float* W = which ? W2 : W1;
    short* Wp = which ? Wp2 : Wp1;
    int col = t4 * 16 + (lane & 15);
    int kr0 = kc * 32 + 8 * (lane >> 4);
    bf16x8 v;
#pragma unroll
    for (int j = 0; j < 8; ++j) v[j] = f2bf(W[(k * CC + kr0 + j) * CC + col]);
    *(bf16x8*)(Wp + ((long)f2 * 64 + lane) * 8) = v;
}

// ---- kernel 3: BN1+ReLU -> bf16 X1; also zero the "missing neighbor" row NS
// in both X1 and X2 (ws is re-poisoned 0xAA before every launch). ----
__global__ void bn1_to_bf16(const float* __restrict__ x, const float* __restrict__ coeffs,
                            short* __restrict__ X1, short* __restrict__ X2) {
    int tid = blockIdx.x * blockDim.x + threadIdx.x;   // one thread per 8 channels
    if (tid < NS * 8) {
        int ch8 = (tid & 7) * 8;
        const float* px = x + (long)tid * 8;
        float4 u = *(const float4*)px;
        float4 w = *(const float4*)(px + 4);
        float o[8] = {u.x, u.y, u.z, u.w, w.x, w.y, w.z, w.w};
        bf16x8 r;
#pragma unroll
        for (int j = 0; j < 8; ++j) {
            float s = coeffs[ch8 + j], bi = coeffs[64 + ch8 + j];
            float y = fmaxf(fmaf(o[j], s, bi), 0.f);
            r[j] = f2bf(y);
        }
        *(bf16x8*)(X1 + (long)tid * 8) = r;
    }
    if (blockIdx.x == 0 && threadIdx.x < 64) {
        X1[(long)NS * 64 + threadIdx.x] = 0;
        X2[(long)NS * 64 + threadIdx.x] = 0;
    }
}

// ---- kernel 4/5: implicit-GEMM submanifold conv via 16x16x32 bf16 MFMA.
// One wave handles 32 sites x 64 out-channels: acc[2 m-tiles][4 n-tiles].
// PHASE 1: epilogue = BN2+ReLU -> bf16 X2.  PHASE 2: epilogue = +features -> f32 out.
template <int PHASE>
__global__ __launch_bounds__(256) void subm_conv(
    const short* __restrict__ Xg,      // (NS+1) x 64 bf16, row NS == zeros
    const int* __restrict__ nb,        // NS x 27, -1 == missing
    const short* __restrict__ Wp,      // packed fragments
    const float* __restrict__ coeffs,
    const float* __restrict__ feat,    // PHASE 2 residual
    short* __restrict__ Xout,          // PHASE 1 output
    float* __restrict__ yout)          // PHASE 2 output
{
    int lane = threadIdx.x & 63;
    int wv = blockIdx.x * 4 + (threadIdx.x >> 6);
    int base = wv * 32;
    if (base >= NS) return;            // NS % 32 == 0: no per-site guards needed
    int r15 = lane & 15, hi = lane >> 4;
    int site0 = base + r15;
    int site1 = base + 16 + r15;

    f32x4 acc[2][4] = {};
    const bf16x8* wpv = (const bf16x8*)Wp;

    for (int k = 0; k < K3; ++k) {
        int i0 = nb[site0 * K3 + k];
        int i1 = nb[site1 * K3 + k];
        int q0 = (i0 < 0) ? NS : i0;   // missing -> zero row
        int q1 = (i1 < 0) ? NS : i1;
        const short* p0 = Xg + (long)q0 * 64 + hi * 8;
        const short* p1 = Xg + (long)q1 * 64 + hi * 8;
        bf16x8 a00 = *(const bf16x8*)p0;          // k-chunk 0..31
        bf16x8 a01 = *(const bf16x8*)(p0 + 32);   // k-chunk 32..63
        bf16x8 a10 = *(const bf16x8*)p1;
        bf16x8 a11 = *(const bf16x8*)(p1 + 32);
        const bf16x8* bp = wpv + (long)k * 8 * 64 + lane;
#pragma unroll
        for (int t4 = 0; t4 < 4; ++t4) {
            bf16x8 b0 = bp[t4 * 64];         // kc=0 fragment
            bf16x8 b1 = bp[(4 + t4) * 64];   // kc=1 fragment
            acc[0][t4] = __builtin_amdgcn_mfma_f32_16x16x32_bf16(a00, b0, acc[0][t4], 0, 0, 0);
            acc[1][t4] = __builtin_amdgcn_mfma_f32_16x16x32_bf16(a10, b0, acc[1][t4], 0, 0, 0);
            acc[0][t4] = __builtin_amdgcn_mfma_f32_16x16x32_bf16(a01, b1, acc[0][t4], 0, 0, 0);
            acc[1][t4] = __builtin_amdgcn_mfma_f32_16x16x32_bf16(a11, b1, acc[1][t4], 0, 0, 0);
        }
    }

    // epilogue; C/D layout: col = lane&15, row = (lane>>4)*4 + reg  (m89)
#pragma unroll
    for (int mt = 0; mt < 2; ++mt) {
#pragma unroll
        for (int t4 = 0; t4 < 4; ++t4) {
            int col = t4 * 16 + r15;
            float sc = 0.f, bi = 0.f;
            if (PHASE == 1) { sc = coeffs[128 + col]; bi = coeffs[192 + col]; }
#pragma unroll
            for (int r = 0; r < 4; ++r) {
                int row = base + mt * 16 + hi * 4 + r;
                long off = (long)row * 64 + col;
                float v = acc[mt][t4][r];
                if (PHASE == 1) {
                    float y = fmaxf(fmaf(v, sc, bi), 0.f);
                    Xout[off] = f2bf(y);
                } else {
                    yout[off] = feat[off] + v;
                }
            }
        }
    }
}

extern "C" void kernel_launch(void* const* d_in, const int* in_sizes, int n_in,
                              void* d_out, int out_size, void* d_ws, size_t ws_size,
                              hipStream_t stream) {
    const float* feat = (const float*)d_in[0];
    const int*   nb   = (const int*)d_in[1];
    const float* g1 = (const float*)d_in[2];
    const float* b1 = (const float*)d_in[3];
    const float* m1 = (const float*)d_in[4];
    const float* v1 = (const float*)d_in[5];
    const float* W1 = (const float*)d_in[6];
    const float* g2 = (const float*)d_in[7];
    const float* b2 = (const float*)d_in[8];
    const float* m2 = (const float*)d_in[9];
    const float* v2 = (const float*)d_in[10];
    const float* W2 = (const float*)d_in[11];
    float* out = (float*)d_out;

    // ws layout (all offsets 128B-aligned):
    //   X1: (NS+16)*64 bf16 = 12,802,048 B
    //   X2: same
    //   Wp1/Wp2: 27*8*64*8 bf16 = 221,184 B each
    //   coeffs: 256 f32
    char* ws = (char*)d_ws;
    short* X1 = (short*)ws;
    short* X2 = (short*)(ws + 12802048);
    short* Wp1 = (short*)(ws + 25604096);
    short* Wp2 = (short*)(ws + 25604096 + 221184);
    float* coeffs = (float*)(ws + 25604096 + 2 * 221184);

    prep_coeffs<<<1, 128, 0, stream>>>(g1, b1, m1, v1, g2, b2, m2, v2, coeffs);
    pack_w<<<108, 256, 0, stream>>>(W1, W2, Wp1, Wp2);
    bn1_to_bf16<<<3125, 256, 0, stream>>>(feat, coeffs, X1, X2);
    subm_conv<1><<<782, 256, 0, stream>>>(X1, nb, Wp1, coeffs, nullptr, X2, nullptr);
    subm_conv<2><<<782, 256, 0, stream>>>(X2, nb, Wp2, coeffs, feat, nullptr, out);
}

// Round 7
// 227.001 us; speedup vs baseline: 1.1918x; 1.1918x over previous
//
#include <hip/hip_runtime.h>
#include <hip/hip_bf16.h>

#define NS 100000
#define CC 64
#define K3 27
#define EPSV 1e-4f
#define NBLK 3125     // 32-site tiles
#define PACKB 108     // weight-pack blocks

typedef __attribute__((ext_vector_type(4))) float f32x4;
typedef __attribute__((ext_vector_type(8))) short bf16x8;

// round-to-nearest-even f32 -> bf16 bits
__device__ __forceinline__ short f2bf(float f) {
    union { float f; unsigned u; } uf; uf.f = f;
    unsigned r = (uf.u + 0x7fffu + ((uf.u >> 16) & 1u)) >> 16;
    return (short)r;
}

// ---- prepare: blocks [0,NBLK) do BN1+ReLU->bf16 X1 (+ zero rows);
//      blocks [NBLK,NBLK+PACKB) pack W1/W2 into MFMA B-fragments. ----
// B-fragment fi = k*8 + kc*4 + t4; lane l holds 8 contiguous-k elements
// B[kc*32 + 8*(l>>4) + j][t4*16 + (l&15)], stored at (fi*64+l)*8.
__global__ __launch_bounds__(256) void prepare(
    const float* __restrict__ x,
    const float* __restrict__ g1, const float* __restrict__ b1,
    const float* __restrict__ m1, const float* __restrict__ v1,
    const float* __restrict__ W1, const float* __restrict__ W2,
    short* __restrict__ X1, short* __restrict__ X2,
    short* __restrict__ Wp1, short* __restrict__ Wp2)
{
    int blk = blockIdx.x;
    if (blk < NBLK) {
        int tid = blk * 256 + threadIdx.x;        // NS*8 threads, one per 8 channels
        int ch8 = (tid & 7) * 8;
        float4 ga = *(const float4*)(g1 + ch8), gb = *(const float4*)(g1 + ch8 + 4);
        float4 ba = *(const float4*)(b1 + ch8), bb = *(const float4*)(b1 + ch8 + 4);
        float4 ma = *(const float4*)(m1 + ch8), mb = *(const float4*)(m1 + ch8 + 4);
        float4 va = *(const float4*)(v1 + ch8), vb = *(const float4*)(v1 + ch8 + 4);
        float g[8] = {ga.x,ga.y,ga.z,ga.w,gb.x,gb.y,gb.z,gb.w};
        float b[8] = {ba.x,ba.y,ba.z,ba.w,bb.x,bb.y,bb.z,bb.w};
        float m[8] = {ma.x,ma.y,ma.z,ma.w,mb.x,mb.y,mb.z,mb.w};
        float vv[8] = {va.x,va.y,va.z,va.w,vb.x,vb.y,vb.z,vb.w};
        const float* px = x + (long)tid * 8;
        float4 u = *(const float4*)px;
        float4 w = *(const float4*)(px + 4);
        float o[8] = {u.x,u.y,u.z,u.w,w.x,w.y,w.z,w.w};
        bf16x8 r;
#pragma unroll
        for (int j = 0; j < 8; ++j) {
            float s = g[j] * rsqrtf(vv[j] + EPSV);
            float bi = b[j] - m[j] * s;
            r[j] = f2bf(fmaxf(fmaf(o[j], s, bi), 0.f));
        }
        *(bf16x8*)(X1 + (long)tid * 8) = r;
        if (blk == 0 && threadIdx.x < 64) {       // zero "missing neighbor" row
            X1[(long)NS * 64 + threadIdx.x] = 0;
            X2[(long)NS * 64 + threadIdx.x] = 0;
        }
    } else {
        int t = (blk - NBLK) * 256 + threadIdx.x; // 2*27*8*64 = 27648 threads
        if (t >= 2 * K3 * 8 * 64) return;
        int lane = t & 63;
        int f = t >> 6;
        int which = f / (K3 * 8);
        int f2 = f % (K3 * 8);
        int k = f2 >> 3, kc = (f2 >> 2) & 1, t4 = f2 & 3;
        const float* W = which ? W2 : W1;
        short* Wp = which ? Wp2 : Wp1;
        int col = t4 * 16 + (lane & 15);
        int kr0 = kc * 32 + 8 * (lane >> 4);
        bf16x8 v;
#pragma unroll
        for (int j = 0; j < 8; ++j) v[j] = f2bf(W[(k * CC + kr0 + j) * CC + col]);
        *(bf16x8*)(Wp + ((long)f2 * 64 + lane) * 8) = v;
    }
}

// ---- conv: block = one 32-site tile; the 4 waves k-split the 27 offsets
// (k = w + 4j), partial sums combined via LDS. 12500 waves total.
// PHASE 1: BN2+ReLU -> bf16 X2.  PHASE 2: +features -> f32 out. ----
template <int PHASE>
__global__ __launch_bounds__(256, 4) void subm_conv(
    const short* __restrict__ Xg,     // (NS+1) x 64 bf16, row NS zeros
    const int* __restrict__ nb,
    const short* __restrict__ Wp,
    const float* __restrict__ g2, const float* __restrict__ b2,
    const float* __restrict__ m2, const float* __restrict__ v2,
    const float* __restrict__ feat,
    short* __restrict__ Xout, float* __restrict__ yout)
{
    __shared__ float red[4][32][64];       // 32 KB partial sums
    __shared__ float s2c[64], b2c[64];     // PHASE1 BN2 coeffs
    int lane = threadIdx.x & 63;
    int w = threadIdx.x >> 6;
    int base = blockIdx.x * 32;
    int r15 = lane & 15, hi = lane >> 4;
    int site0 = base + r15, site1 = base + 16 + r15;

    if (PHASE == 1 && threadIdx.x < 64) {
        float s = g2[threadIdx.x] * rsqrtf(v2[threadIdx.x] + EPSV);
        s2c[threadIdx.x] = s;
        b2c[threadIdx.x] = b2[threadIdx.x] - m2[threadIdx.x] * s;
    }

    // hoist all neighbor indices for this wave's 7 offsets (k = w+4j; k=27 padded)
    int q0[7], q1[7];
#pragma unroll
    for (int j = 0; j < 7; ++j) {
        int k = w + 4 * j;
        int i0 = (k < K3) ? nb[site0 * K3 + k] : -1;
        int i1 = (k < K3) ? nb[site1 * K3 + k] : -1;
        q0[j] = (i0 < 0) ? NS : i0;
        q1[j] = (i1 < 0) ? NS : i1;
    }

    f32x4 acc[2][4] = {};
    const bf16x8* wpv = (const bf16x8*)Wp;
#pragma unroll
    for (int j = 0; j < 7; ++j) {
        int k = w + 4 * j;
        int kk = (k < K3) ? k : 0;         // safe B addr; A is zero row when padded
        const short* p0 = Xg + (long)q0[j] * 64 + hi * 8;
        const short* p1 = Xg + (long)q1[j] * 64 + hi * 8;
        bf16x8 a00 = *(const bf16x8*)p0;
        bf16x8 a01 = *(const bf16x8*)(p0 + 32);
        bf16x8 a10 = *(const bf16x8*)p1;
        bf16x8 a11 = *(const bf16x8*)(p1 + 32);
        const bf16x8* bp = wpv + (long)kk * 8 * 64 + lane;
#pragma unroll
        for (int t4 = 0; t4 < 4; ++t4) {
            bf16x8 b0 = bp[t4 * 64];
            bf16x8 b1 = bp[(4 + t4) * 64];
            acc[0][t4] = __builtin_amdgcn_mfma_f32_16x16x32_bf16(a00, b0, acc[0][t4], 0, 0, 0);
            acc[1][t4] = __builtin_amdgcn_mfma_f32_16x16x32_bf16(a10, b0, acc[1][t4], 0, 0, 0);
            acc[0][t4] = __builtin_amdgcn_mfma_f32_16x16x32_bf16(a01, b1, acc[0][t4], 0, 0, 0);
            acc[1][t4] = __builtin_amdgcn_mfma_f32_16x16x32_bf16(a11, b1, acc[1][t4], 0, 0, 0);
        }
    }

    // C/D layout (m89): col = t4*16 + (lane&15), row = mt*16 + (lane>>4)*4 + r
#pragma unroll
    for (int mt = 0; mt < 2; ++mt)
#pragma unroll
        for (int t4 = 0; t4 < 4; ++t4)
#pragma unroll
            for (int r = 0; r < 4; ++r)
                red[w][mt * 16 + hi * 4 + r][t4 * 16 + r15] = acc[mt][t4][r];
    __syncthreads();

    int t = threadIdx.x;
    int lr = t >> 3, c0 = (t & 7) * 8;
    int row = base + lr;
    float s[8];
#pragma unroll
    for (int c = 0; c < 8; ++c)
        s[c] = red[0][lr][c0 + c] + red[1][lr][c0 + c] +
               red[2][lr][c0 + c] + red[3][lr][c0 + c];
    if (PHASE == 1) {
        bf16x8 o;
#pragma unroll
        for (int c = 0; c < 8; ++c)
            o[c] = f2bf(fmaxf(fmaf(s[c], s2c[c0 + c], b2c[c0 + c]), 0.f));
        *(bf16x8*)(Xout + (long)row * 64 + c0) = o;
    } else {
        const float* fp = feat + (long)row * 64 + c0;
        float4 f0 = *(const float4*)fp, f1 = *(const float4*)(fp + 4);
        float4 o0 = {s[0] + f0.x, s[1] + f0.y, s[2] + f0.z, s[3] + f0.w};
        float4 o1 = {s[4] + f1.x, s[5] + f1.y, s[6] + f1.z, s[7] + f1.w};
        float* op = yout + (long)row * 64 + c0;
        *(float4*)op = o0;
        *(float4*)(op + 4) = o1;
    }
}

extern "C" void kernel_launch(void* const* d_in, const int* in_sizes, int n_in,
                              void* d_out, int out_size, void* d_ws, size_t ws_size,
                              hipStream_t stream) {
    const float* feat = (const float*)d_in[0];
    const int*   nb   = (const int*)d_in[1];
    const float* g1 = (const float*)d_in[2];
    const float* b1 = (const float*)d_in[3];
    const float* m1 = (const float*)d_in[4];
    const float* v1 = (const float*)d_in[5];
    const float* W1 = (const float*)d_in[6];
    const float* g2 = (const float*)d_in[7];
    const float* b2 = (const float*)d_in[8];
    const float* m2 = (const float*)d_in[9];
    const float* v2 = (const float*)d_in[10];
    const float* W2 = (const float*)d_in[11];
    float* out = (float*)d_out;

    // ws layout: X1 (NS+16)*64 bf16 = 12,802,048 B; X2 same; Wp1/Wp2 221,184 B each
    char* ws = (char*)d_ws;
    short* X1 = (short*)ws;
    short* X2 = (short*)(ws + 12802048);
    short* Wp1 = (short*)(ws + 25604096);
    short* Wp2 = (short*)(ws + 25604096 + 221184);

    prepare<<<NBLK + PACKB, 256, 0, stream>>>(feat, g1, b1, m1, v1, W1, W2,
                                              X1, X2, Wp1, Wp2);
    subm_conv<1><<<NBLK, 256, 0, stream>>>(X1, nb, Wp1, g2, b2, m2, v2,
                                           nullptr, X2, nullptr);
    subm_conv<2><<<NBLK, 256, 0, stream>>>(X2, nb, Wp2, g2, b2, m2, v2,
                                           feat, nullptr, out);
}